// Round 5
// baseline (357.616 us; speedup 1.0000x reference)
//
#include <hip/hip_runtime.h>
#include <math.h>

#define H    128
#define TT   128
#define CH   8            // steps per chunk/flag
#define NCH  (TT / CH)    // 16

// ws float offsets
#define OFF_H1V   0                 // [b][t][256]  h1 | v      : 262144 floats
#define OFF_PARTS 262144            // [b][t][1024] z2 | ad     : 1048576 floats
#define OFF_CNT   1441792           // int counters (poisoned 0xAA -> negative)

typedef __attribute__((ext_vector_type(2))) float f2;

__device__ __forceinline__ float sigf(float x)       { return 1.0f / (1.0f + __expf(-x)); }
__device__ __forceinline__ float tanhf_fast(float x) { return 1.0f - 2.0f / (1.0f + __expf(2.0f * x)); }

// sum across the 2-lane pair (xor1) via DPP quad_perm [1,0,3,2]
__device__ __forceinline__ float pair_sum(float v) {
    int t = __builtin_amdgcn_update_dpp(0, __float_as_int(v), 0xB1, 0xF, 0xF, true);
    return v + __int_as_float(t);
}
// 4-lane sum (used only in C's chunk reduce)
__device__ __forceinline__ float quad_sum(float v) {
    int t = __builtin_amdgcn_update_dpp(0, __float_as_int(v), 0xB1, 0xF, 0xF, true);
    v += __int_as_float(t);
    t = __builtin_amdgcn_update_dpp(0, __float_as_int(v), 0x4E, 0xF, 0xF, true);
    v += __int_as_float(t);
    return v;
}

// Cheap spin: RELAXED polls, then ONE acquire load for the synchronizes-with edge.
__device__ __forceinline__ void wait_ge(int* ptr, int val) {
    while (__hip_atomic_load(ptr, __ATOMIC_RELAXED, __HIP_MEMORY_SCOPE_AGENT) < val)
        __builtin_amdgcn_s_sleep(1);
    (void)__hip_atomic_load(ptr, __ATOMIC_ACQUIRE, __HIP_MEMORY_SCOPE_AGENT);
}

// Per-step barrier: LDS-only drain (global stores stay in flight until chunk end).
#define BARRIER_LGKM() do { \
    asm volatile("s_waitcnt lgkmcnt(0)" ::: "memory"); \
    __builtin_amdgcn_s_barrier(); \
    asm volatile("" ::: "memory"); \
} while (0)

// Chunk-boundary barrier: full drain so r0's agent-scope release publishes all.
#define BARRIER_ALL() do { \
    asm volatile("s_waitcnt vmcnt(0) lgkmcnt(0)" ::: "memory"); \
    __builtin_amdgcn_s_barrier(); \
    asm volatile("" ::: "memory"); \
} while (0)

// Load one float4 of weights as two packed f2 pairs, pinned in arch VGPRs.
#define DECLW4(nm, src) \
    float4 _t_##nm = (src); \
    f2 nm##_a = {_t_##nm.x, _t_##nm.y}; \
    f2 nm##_b = {_t_##nm.z, _t_##nm.w}; \
    asm volatile("" : "+v"(nm##_a), "+v"(nm##_b));

#define DECLG(g, ptr) \
    DECLW4(g##0,(ptr)[0])  DECLW4(g##1,(ptr)[1])  DECLW4(g##2,(ptr)[2])  DECLW4(g##3,(ptr)[3]) \
    DECLW4(g##4,(ptr)[4])  DECLW4(g##5,(ptr)[5])  DECLW4(g##6,(ptr)[6])  DECLW4(g##7,(ptr)[7]) \
    DECLW4(g##8,(ptr)[8])  DECLW4(g##9,(ptr)[9])  DECLW4(g##10,(ptr)[10]) DECLW4(g##11,(ptr)[11]) \
    DECLW4(g##12,(ptr)[12]) DECLW4(g##13,(ptr)[13]) DECLW4(g##14,(ptr)[14]) DECLW4(g##15,(ptr)[15])

// 2-lane k-split: thread (rg,p) holds rows {rg,rg+128,rg+256,rg+384},
// k-slice [64p, 64p+64) -> 256 floats/thread as 128 f2 (arch-VGPR resident
// under the 512-reg budget of 1 wave/EU; one wave per SIMD, 4-wave barriers).
#define LOADW_ALL(W) \
    const float4* wpa_ = (const float4*)((W) + (size_t)(rg)       * H + p * 64); \
    const float4* wpb_ = (const float4*)((W) + (size_t)(rg + 128) * H + p * 64); \
    const float4* wpc_ = (const float4*)((W) + (size_t)(rg + 256) * H + p * 64); \
    const float4* wpd_ = (const float4*)((W) + (size_t)(rg + 384) * H + p * 64); \
    DECLG(wa, wpa_) DECLG(wb, wpb_) DECLG(wc, wpc_) DECLG(wd, wpd_)

// Packed dual-FMA: acc(lo,hi) += w(lo,hi) * h(lo,hi).
#define PKFMA(acc, w, h) \
    asm("v_pk_fma_f32 %0, %1, %2, %0" : "+v"(acc) : "v"(w), "v"(h));

#define FMA1(nm, hA, hB, acc) PKFMA(acc, nm##_a, hA) PKFMA(acc, nm##_b, hB)

#define DOTJ(j) { \
    f2 hA_ = {hv##j.x, hv##j.y}; f2 hB_ = {hv##j.z, hv##j.w}; \
    FMA1(wa##j, hA_, hB_, q0) FMA1(wb##j, hA_, hB_, q1) \
    FMA1(wc##j, hA_, hB_, q2) FMA1(wd##j, hA_, hB_, q3) }

// 16 b128 broadcast reads (2 distinct addrs/wave = conflict-free) + 128 pk_fma
// + single-DPP pair reduction -> a0..a3 = full gate dots (both lanes).
#define DOT_BODY(HBASE) \
    const float4* _hp4 = (const float4*)(HBASE); \
    float4 hv0=_hp4[0],hv1=_hp4[1],hv2=_hp4[2],hv3=_hp4[3], \
           hv4=_hp4[4],hv5=_hp4[5],hv6=_hp4[6],hv7=_hp4[7], \
           hv8=_hp4[8],hv9=_hp4[9],hv10=_hp4[10],hv11=_hp4[11], \
           hv12=_hp4[12],hv13=_hp4[13],hv14=_hp4[14],hv15=_hp4[15]; \
    f2 q0={0.f,0.f},q1={0.f,0.f},q2={0.f,0.f},q3={0.f,0.f}; \
    DOTJ(0) DOTJ(1) DOTJ(2) DOTJ(3) DOTJ(4) DOTJ(5) DOTJ(6) DOTJ(7) \
    DOTJ(8) DOTJ(9) DOTJ(10) DOTJ(11) DOTJ(12) DOTJ(13) DOTJ(14) DOTJ(15) \
    float a0=pair_sum(q0.x+q0.y), a1=pair_sum(q1.x+q1.y), \
          a2=pair_sum(q2.x+q2.y), a3=pair_sum(q3.x+q3.y);

// ---------------------------------------------------------------------------
// Overlapped 4-role pipeline, one CU per (role,batch): 32 blocks x 256 thr.
//   role 0 = A : layer-1 recurrence (w_hh0)        -> h1[t], v[t]
//   role 1 = B1: w_ih1 @ h1 (chunked)              -> parts[.., 0:512)
//   role 2 = B2: w_ih1 @ v  (chunked)              -> parts[.., 512:1024)
//   role 3 = C : w_hh1 @ h2 + elementwise -> DIAGONAL-only output scatter
// Output zeros are pre-written by hipMemsetAsync before this kernel.
// ---------------------------------------------------------------------------
__global__ __launch_bounds__(256, 1)
void pipe_kernel(const float* __restrict__ x,
                 const float* __restrict__ w_ih0,
                 const float* __restrict__ w_hh0,
                 const float* __restrict__ b_ih0,
                 const float* __restrict__ b_hh0,
                 const float* __restrict__ w_ih1,
                 const float* __restrict__ w_hh1,
                 const float* __restrict__ b_ih1,
                 const float* __restrict__ b_hh1,
                 const float* __restrict__ w_out,
                 float* __restrict__ ws,
                 float* __restrict__ outp) {
    const int role = blockIdx.x >> 3;
    const int b    = blockIdx.x & 7;
    const int r    = threadIdx.x;        // 0..255
    const int rg   = r >> 1, p = r & 1;  // 128 row-groups x 2 k-halves

    int* cntA  = (int*)ws + OFF_CNT       + b * 32;
    int* cntB1 = (int*)ws + OFF_CNT + 256 + b * 32;
    int* cntB2 = (int*)ws + OFF_CNT + 512 + b * 32;
    float* h1v = ws + OFF_H1V + (size_t)b * TT * 256;

    __shared__ float hbuf[2][128];    // recurrent state, plain layout
    __shared__ float u_s[TT];
    __shared__ float scr[256];
    __shared__ float hb[CH * 128];    // B chunk staging
    __shared__ float gbuf[CH][128];   // C: per-chunk unreduced g

    if (role == 0) {
        // ===================== Stage A: layer-1 recurrence =====================
        LOADW_ALL(w_hh0)
        const float b0 = b_ih0[rg]       + b_hh0[rg];
        const float b1 = b_ih0[rg + 128] + b_hh0[rg + 128];
        const float b2 = b_ih0[rg + 256] + b_hh0[rg + 256];
        const float b3 = b_ih0[rg + 384] + b_hh0[rg + 384];
        const float wi0 = w_ih0[rg], wi1 = w_ih0[rg + 128];
        const float wi2 = w_ih0[rg + 256], wi3 = w_ih0[rg + 384];
        {   // u[t] = trace(x[b,t]) cooperatively (2 partials per t)
            const float* xb = x + (size_t)(b * TT + (r & 127)) * 1024;
            const int pq = r >> 7;               // 0..1
            float u = 0.f;
#pragma unroll
            for (int i = 0; i < 16; i++) u += xb[(pq * 16 + i) * 33];
            scr[r] = u;
        }
        if (r < 128) { hbuf[0][r] = 0.f; hbuf[1][r] = 0.f; }
        __syncthreads();
        if (r < TT) u_s[r] = scr[r] + scr[r + 128];
        __syncthreads();

        float c1 = 0.f;
        float hn_prev = 0.f, vn_prev = 0.f;
        for (int t = 0; t < TT; t++) {
            // publish PREVIOUS step's h1v early (issues during this step's work)
            if (t & (CH - 1)) {
                if (p == 0) h1v[(t - 1) * 256 + rg] = hn_prev;
                else        h1v[(t - 1) * 256 + 128 + rg] = vn_prev;
            }
            const float u = u_s[t];
            const float* hc = hbuf[t & 1];
            float* hx = (float*)hbuf[(t & 1) ^ 1];
            DOT_BODY(hc + p * 64)
            float z0 = a0 + fmaf(wi0, u, b0);
            float z1 = a1 + fmaf(wi1, u, b1);
            float z2 = a2 + fmaf(wi2, u, b2);
            float z3 = a3 + fmaf(wi3, u, b3);
            float gi = sigf(z0), gf = sigf(z1), gg = tanhf_fast(z2), go = sigf(z3);
            float di = gi * (1.f - gi) * wi0, df = gf * (1.f - gf) * wi1;
            float dg = (1.f - gg * gg) * wi2, dd = go * (1.f - go) * wi3;
            float dc = df * c1 + di * gg + gi * dg;
            c1 = gf * c1 + gi * gg;
            float th = tanhf_fast(c1);
            float hn = go * th;
            float vn = dd * th + go * (1.f - th * th) * dc;
            if (p == 0) hx[rg] = hn;                    // one writer per h-index
            if ((t & (CH - 1)) == CH - 1) {
                if (p == 0) h1v[t * 256 + rg] = hn;     // chunk end: publish NOW
                else        h1v[t * 256 + 128 + rg] = vn;
                BARRIER_ALL();   // drain chunk's global stores before the flag
                if (r == 0)
                    __hip_atomic_store(cntA, t + 1, __ATOMIC_RELEASE, __HIP_MEMORY_SCOPE_AGENT);
            } else {
                hn_prev = hn; vn_prev = vn;
                BARRIER_LGKM();  // LDS recurrence state only — no vmcnt drain
            }
        }
    } else if (role == 1 || role == 2) {
        // ============ Stages B1/B2: w_ih1 @ (h1 | v), chunk-parallel ============
        LOADW_ALL(w_ih1)
        int* myCnt = (role == 2) ? cntB2 : cntB1;
        const float* hsrc = h1v + ((role == 2) ? 128 : 0);
        float* pbase = ws + OFF_PARTS + (size_t)b * TT * 1024 + ((role == 2) ? 512 : 0);
        for (int c = 0; c < NCH; c++) {
            if (r == 0) wait_ge(cntA, (c + 1) * CH);
            __syncthreads();
            {   // stage chunk: 256 threads x 1 float4 = 8t x 128 floats
                int tl = r >> 5, k4 = r & 31;
                float4 v = *(const float4*)(hsrc + (size_t)(c * CH + tl) * 256 + k4 * 4);
                *(float4*)&hb[tl * 128 + k4 * 4] = v;
            }
            __syncthreads();
#pragma unroll
            for (int tl = 0; tl < CH; tl++) {
                DOT_BODY(hb + tl * 128 + p * 64)
                // p0 stores gates {0,1}, p1 stores gates {2,3} -> C reads float4
                f2 st;
                if (p == 0) { st.x = a0; st.y = a1; } else { st.x = a2; st.y = a3; }
                *(f2*)(pbase + (size_t)(c * CH + tl) * 1024 + rg * 4 + p * 2) = st;
            }
            BARRIER_ALL();   // drain all chunk stores before flag
            if (r == 0)
                __hip_atomic_store(myCnt, (c + 1) * CH, __ATOMIC_RELEASE, __HIP_MEMORY_SCOPE_AGENT);
        }
    } else {
        // ==== Stage C: w_hh1 @ h2 + layer-2 elementwise + diag-only scatter ====
        LOADW_ALL(w_hh1)
        const float b0 = b_ih1[rg]       + b_hh1[rg];
        const float b1 = b_ih1[rg + 128] + b_hh1[rg + 128];
        const float b2 = b_ih1[rg + 256] + b_hh1[rg + 256];
        const float b3 = b_ih1[rg + 384] + b_hh1[rg + 384];
        const float wo = w_out[rg];
        if (r < 128) { hbuf[0][r] = 0.f; hbuf[1][r] = 0.f; }
        __syncthreads();
        const float* parts = ws + OFF_PARTS + (size_t)b * TT * 1024;
        float c2 = 0.f;
        for (int c = 0; c < NCH; c++) {
            if (r == 0) { wait_ge(cntB1, (c + 1) * CH); wait_ge(cntB2, (c + 1) * CH); }
            __syncthreads();
#pragma unroll
            for (int tl = 0; tl < CH; tl++) {
                const int t = c * CH + tl;
                // issue partial loads FIRST; L2 latency hides under the dot
                const float* pt = parts + (size_t)t * 1024 + rg * 4;
                float4 zf = *(const float4*)pt;
                float4 af = *(const float4*)(pt + 512);
                const float* hc = hbuf[t & 1];
                float* hx = (float*)hbuf[(t & 1) ^ 1];
                DOT_BODY(hc + p * 64)
                float z0 = a0 + b0 + zf.x;
                float z1 = a1 + b1 + zf.y;
                float z2 = a2 + b2 + zf.z;
                float z3 = a3 + b3 + zf.w;
                float gi = sigf(z0), gf = sigf(z1), gg = tanhf_fast(z2), go = sigf(z3);
                float di = gi * (1.f - gi) * af.x, df = gf * (1.f - gf) * af.y;
                float dg = (1.f - gg * gg) * af.z, dd = go * (1.f - go) * af.w;
                float dc = df * c2 + di * gg + gi * dg;
                c2 = gf * c2 + gi * gg;
                float th = tanhf_fast(c2);
                if (p == 0) hx[rg] = go * th;
                float dh2 = dd * th + go * (1.f - th * th) * dc;
                if (p == 0) gbuf[tl][rg] = wo * dh2;   // unreduced, LDS
                BARRIER_LGKM();   // hbuf + gbuf are LDS-only -> no vmcnt drain
            }
            // ---- reduce chunk's g and scatter ONLY the 32 diagonal scalars ----
            {
                const int w = r >> 6, l = r & 63;      // wave w handles 2 t's
#pragma unroll
                for (int tt = 0; tt < 2; tt++) {
                    const int t8 = w * 2 + tt;
                    float v = gbuf[t8][l] + gbuf[t8][l + 64];
                    v = quad_sum(v);
                    v += __shfl_xor(v, 4, 64);
                    v += __shfl_xor(v, 8, 64);
                    v += __shfl_xor(v, 16, 64);
                    v += __shfl_xor(v, 32, 64);
                    if (l == 0) scr[t8] = v;
                }
                BARRIER_LGKM();
                {                                       // 8 t x 32 diag elements
                    const int tl = r >> 5, d = r & 31;
                    outp[(size_t)(b * TT + c * CH + tl) * 1024 + d * 33] = scr[tl];
                }
            }
        }
    }
}

extern "C" void kernel_launch(void* const* d_in, const int* in_sizes, int n_in,
                              void* d_out, int out_size, void* d_ws, size_t ws_size,
                              hipStream_t stream) {
    const float* x     = (const float*)d_in[0];
    const float* w_ih0 = (const float*)d_in[1];
    const float* w_hh0 = (const float*)d_in[2];
    const float* b_ih0 = (const float*)d_in[3];
    const float* b_hh0 = (const float*)d_in[4];
    const float* w_ih1 = (const float*)d_in[5];
    const float* w_hh1 = (const float*)d_in[6];
    const float* b_ih1 = (const float*)d_in[7];
    const float* b_hh1 = (const float*)d_in[8];
    const float* w_out = (const float*)d_in[9];
    // d_in[10] = b_out: constant offset, zero derivative -> unused

    float* ws = (float*)d_ws;   // counters rely on 0xAA poison (<0 as int)

    // Zero the output (31/32 of it stays zero; pipe_kernel scatters diagonals).
    hipMemsetAsync(d_out, 0, (size_t)out_size, stream);

    pipe_kernel<<<dim3(32), dim3(256), 0, stream>>>(x, w_ih0, w_hh0, b_ih0, b_hh0,
                                                    w_ih1, w_hh1, b_ih1, b_hh1, w_out,
                                                    ws, (float*)d_out);
}